// Round 5
// baseline (662.962 us; speedup 1.0000x reference)
//
#include <hip/hip_runtime.h>
#include <math.h>

#define N 1024
#define BATCH 16
#define CH 3
#define BC 48
#define OUTHW 224
#define KSCALE (1024.0f / 224.0f)
#define SCALE  (224.0f / 1024.0f)
#define ABYTES ((size_t)BC * N * N * 8)      // 384 MiB complex workspace
#define T1OFF  (768 * 2048)                  // float offset of T1 inside each image's slab
#define LP(i)  ((i) + ((i) >> 5))            // bank-depad for the resize gather

// (ar,ai)*(br,bi) -> (dr,di); safe when d aliases a
#define CMUL(dr, di, ar, ai, br, bi) do {                         \
    float _r = (ar) * (br) - (ai) * (bi);                         \
    float _i = (ar) * (bi) + (ai) * (br);                         \
    (dr) = _r; (di) = _i; } while (0)

#define RADIX4(ar,ai,br,bi,cr,ci,dr,di, o0r,o0i,o1r,o1i,o2r,o2i,o3r,o3i) do { \
    float u0r=(ar)+(cr), u0i=(ai)+(ci);                           \
    float u1r=(ar)-(cr), u1i=(ai)-(ci);                           \
    float u2r=(br)+(dr), u2i=(bi)+(di);                           \
    float u3r=(bi)-(di), u3i=(dr)-(br);                           \
    (o0r)=u0r+u2r; (o0i)=u0i+u2i;                                 \
    (o1r)=u1r+u3r; (o1i)=u1i+u3i;                                 \
    (o2r)=u0r-u2r; (o2i)=u0i-u2i;                                 \
    (o3r)=u1r-u3r; (o3i)=u1i-u3i; } while (0)

// In-register natural-order 16-pt forward DFT (radix-4 x radix-4).
__device__ __forceinline__ void dft16(float* xr, float* xi) {
  const float W16R[4][4] = {
    {1.f, 1.f, 1.f, 1.f},
    {1.f,  0.9238795325f,  0.7071067812f,  0.3826834324f},
    {1.f,  0.7071067812f,  0.0f,          -0.7071067812f},
    {1.f,  0.3826834324f, -0.7071067812f, -0.9238795325f}};
  const float W16I[4][4] = {
    {0.f, 0.f, 0.f, 0.f},
    {0.f, -0.3826834324f, -0.7071067812f, -0.9238795325f},
    {0.f, -0.7071067812f, -1.0f,          -0.7071067812f},
    {0.f, -0.9238795325f, -0.7071067812f,  0.3826834324f}};
  float tr[16], ti[16];
#pragma unroll
  for (int j = 0; j < 4; ++j) {
    RADIX4(xr[j],xi[j], xr[j+4],xi[j+4], xr[j+8],xi[j+8], xr[j+12],xi[j+12],
           tr[4*j],ti[4*j], tr[4*j+1],ti[4*j+1], tr[4*j+2],ti[4*j+2], tr[4*j+3],ti[4*j+3]);
  }
#pragma unroll
  for (int j = 0; j < 4; ++j) {
    float ar[4], ai_[4];
#pragma unroll
    for (int k = 0; k < 4; ++k) {
      if (j == 0 || k == 0) { ar[k] = tr[j+4*k]; ai_[k] = ti[j+4*k]; }
      else CMUL(ar[k], ai_[k], tr[j+4*k], ti[j+4*k], W16R[j][k], W16I[j][k]);
    }
    RADIX4(ar[0],ai_[0], ar[1],ai_[1], ar[2],ai_[2], ar[3],ai_[3],
           xr[j],xi[j], xr[j+4],xi[j+4], xr[j+8],xi[j+8], xr[j+12],xi[j+12]);
  }
}

// Wave-level 1024-pt FFT, radices [16,16,4] Stockham. xr[k]=x[l+64k] in, X[l+64s] out.
// Single 1088-float per-wave LDS buffer: re/im shuffled SEQUENTIALLY (per-wave
// in-order DS pipe makes the read-then-overwrite WAR safe; wave_barrier pins
// compiler ordering). All LDS patterns <=3-way.
__device__ __forceinline__ void wave_fft1024(float* xr, float* xi, float* s,
                                             const float2* __restrict__ twg, int l) {
  dft16(xr, xi);                       // stage 1 (Ns=1)
  const int wbase = 17 * l;
  const int base2 = l + (l >> 4);
#pragma unroll
  for (int k = 0; k < 16; ++k) s[wbase + k] = xr[k];
  __builtin_amdgcn_wave_barrier();
#pragma unroll
  for (int k = 0; k < 16; ++k) xr[k] = s[base2 + 68 * k];
  __builtin_amdgcn_wave_barrier();
#pragma unroll
  for (int k = 0; k < 16; ++k) s[wbase + k] = xi[k];
  __builtin_amdgcn_wave_barrier();
#pragma unroll
  for (int k = 0; k < 16; ++k) xi[k] = s[base2 + 68 * k];
  __builtin_amdgcn_wave_barrier();
  const int j2 = l & 15;
#pragma unroll
  for (int k = 1; k < 16; ++k) {       // twiddle W256^{j2*k}
    float2 w = twg[4 * j2 * k];
    CMUL(xr[k], xi[k], xr[k], xi[k], w.x, w.y);
  }
  dft16(xr, xi);                       // stage 2 (Ns=16)
  const int ob = 272 * (l >> 4) + j2;
  float tr[16], ti[16];
#pragma unroll
  for (int k = 0; k < 16; ++k) s[ob + 17 * k] = xr[k];
  __builtin_amdgcn_wave_barrier();
#pragma unroll
  for (int m = 0; m < 4; ++m)
#pragma unroll
    for (int k = 0; k < 4; ++k) tr[4 * m + k] = s[base2 + 68 * m + 272 * k];
  __builtin_amdgcn_wave_barrier();
#pragma unroll
  for (int k = 0; k < 16; ++k) s[ob + 17 * k] = xi[k];
  __builtin_amdgcn_wave_barrier();
#pragma unroll
  for (int m = 0; m < 4; ++m)
#pragma unroll
    for (int k = 0; k < 4; ++k) ti[4 * m + k] = s[base2 + 68 * m + 272 * k];
  __builtin_amdgcn_wave_barrier();
#pragma unroll
  for (int m = 0; m < 4; ++m) {        // stage 3 (Ns=256, radix-4)
    const int j = l + 64 * m;
    float ar[4], ai_[4];
    ar[0] = tr[4*m]; ai_[0] = ti[4*m];
#pragma unroll
    for (int k = 1; k < 4; ++k) {      // twiddle W1024^{j*k}, j*k <= 765
      float2 w = twg[j * k];
      CMUL(ar[k], ai_[k], tr[4*m+k], ti[4*m+k], w.x, w.y);
    }
    RADIX4(ar[0],ai_[0], ar[1],ai_[1], ar[2],ai_[2], ar[3],ai_[3],
           xr[m],xi[m], xr[m+4],xi[m+4], xr[m+8],xi[m+8], xr[m+12],xi[m+12]);
  }
  __builtin_amdgcn_wave_barrier();
}

__global__ void k_init(float2* __restrict__ tw, int* __restrict__ mnmx) {
  int g = blockIdx.x * 256 + threadIdx.x;
  if (g < 1024) {
    float ang = -6.283185307179586f * ((float)g / 1024.0f);
    float s, c;
    sincosf(ang, &s, &c);
    tw[g] = make_float2(c, s);
  }
  if (g < BATCH) mnmx[g] = 0x7F800000;
  else if (g < 2 * BATCH) mnmx[g] = 0;
}

// Pass 1: 4 waves/block, 8 consecutive image rows; packed row-pair FFT, Hermitian
// unpack (bins 0..512), transposed write to A^T in two v-range phases (keeps 64B
// chunks with only 17408B block LDS).
__global__ __launch_bounds__(256, 6) void k_rowfft(const float* __restrict__ in,
                                                   float2* __restrict__ A,
                                                   const float2* __restrict__ twg) {
  __shared__ float lds[4352];          // 4 x 1088; overlaid as staged[2][8][260]
  const int t  = threadIdx.x;
  const int w  = t >> 6;
  const int l  = t & 63;
  const int bc  = blockIdx.x >> 7;
  const int h0b = (blockIdx.x & 127) << 3;
  float* swav = lds + w * 1088;
  const float* row0 = in + ((size_t)bc << 20) + ((size_t)(h0b + 2 * w) << 10);
  const float* row1 = row0 + N;
  float xr[16], xi[16];
  const float sgn = (l & 1) ? -1.0f : 1.0f;   // (-1)^(h+w), h0 even / h1 odd
#pragma unroll
  for (int k = 0; k < 16; ++k) {
    xr[k] =  sgn * row0[l + 64*k];
    xi[k] = -sgn * row1[l + 64*k];
  }
  wave_fft1024(xr, xi, swav, twg, l);
  // Hermitian unpack, sequential re/im through the same buffer:
  // A=(P+conj(Q))/2, B=-i(P-conj(Q))/2, Q=Z[(N-i)&1023]
  float arr[9], ari[9], brr[9], bri[9];
#pragma unroll
  for (int s = 0; s < 16; ++s) swav[l + 64*s] = xr[s];
  __builtin_amdgcn_wave_barrier();
#pragma unroll
  for (int s = 0; s < 9; ++s) {
    float qr = swav[(N - (l + 64*s)) & (N - 1)];
    arr[s] = 0.5f * (xr[s] + qr);
    bri[s] = 0.5f * (qr - xr[s]);
  }
  __builtin_amdgcn_wave_barrier();
#pragma unroll
  for (int s = 0; s < 16; ++s) swav[l + 64*s] = xi[s];
  __builtin_amdgcn_wave_barrier();
#pragma unroll
  for (int s = 0; s < 9; ++s) {
    float qi = swav[(N - (l + 64*s)) & (N - 1)];
    ari[s] = 0.5f * (xi[s] - qi);
    brr[s] = 0.5f * (xi[s] + qi);
  }
  // Two-phase staged transposed write: phase p covers v in [260p, 260p+260)
  float* stre = lds;                   // [8][260]
  float* stim = lds + 2080;
  float2* Abc = A + ((size_t)bc << 20);
  const int rr = t & 7, v0 = t >> 3;
#pragma unroll
  for (int p = 0; p < 2; ++p) {
    const int vlo = 260 * p;
    __syncthreads();
#pragma unroll
    for (int s = 0; s < 9; ++s) {
      int i = l + 64*s;
      int dv = i - vlo;
      if (dv >= 0 && dv < 260 && i <= 512) {
        stre[(2*w)     * 260 + dv] = arr[s]; stim[(2*w)     * 260 + dv] = ari[s];
        stre[(2*w + 1) * 260 + dv] = brr[s]; stim[(2*w + 1) * 260 + dv] = bri[s];
      }
    }
    __syncthreads();
#pragma unroll
    for (int i2 = 0; i2 < 9; ++i2) {
      int dv = v0 + 32 * i2;
      int v = vlo + dv;
      if (dv < 260 && v <= 512) {
        Abc[(size_t)v * N + h0b + rr] = make_float2(stre[rr*260 + dv], stim[rr*260 + dv]);
      }
    }
  }
}

// Pass 2: 1 column FFT per wave (A^T rows coalesced, barrier-free FFT),
// log1p|.|, wave minmax -> atomics, fused u-resize (column sx + 2D-Hermitian
// mirror N-sx) with LP-padded spec to kill the ~9-way gather conflict.
__global__ __launch_bounds__(256, 6) void k_colfft(const float2* __restrict__ A,
                                                   float* __restrict__ WSf,
                                                   int* __restrict__ mnmx,
                                                   const float2* __restrict__ twg) {
  __shared__ float lds[4352];
  const int t  = threadIdx.x;
  const int w  = t >> 6;
  const int l  = t & 63;
  const int gw = blockIdx.x * 4 + w;   // 0..BC*513-1 exactly
  const int bc = gw / 513;
  const int sx = gw % 513;
  const int b  = bc / CH;
  float* swav = lds + w * 1088;
  const float2* src = A + ((size_t)bc << 20) + ((size_t)sx << 10);
  float xr[16], xi[16];
#pragma unroll
  for (int k = 0; k < 16; ++k) { float2 v = src[l + 64*k]; xr[k] = v.x; xi[k] = v.y; }
  wave_fft1024(xr, xi, swav, twg, l);
  float lmin = 3.4e38f, lmax = 0.0f;
#pragma unroll
  for (int s = 0; s < 16; ++s) {
    float sp = __logf(1.0f + sqrtf(xr[s]*xr[s] + xi[s]*xi[s]));
    swav[LP(l + 64*s)] = sp;           // LP-padded spec
    lmin = fminf(lmin, sp); lmax = fmaxf(lmax, sp);
  }
#pragma unroll
  for (int off = 32; off; off >>= 1) {
    lmin = fminf(lmin, __shfl_xor(lmin, off));
    lmax = fmaxf(lmax, __shfl_xor(lmax, off));
  }
  if (l == 0) {
    atomicMin(&mnmx[b], __float_as_int(lmin));
    atomicMax(&mnmx[BATCH + b], __float_as_int(lmax));
  }
  __builtin_amdgcn_wave_barrier();
  float* T1 = WSf + ((size_t)bc << 21) + T1OFF;
  const bool mir = (sx != 0) && (sx != 512);
#pragma unroll
  for (int ob = 0; ob < 4; ++ob) {
    int oh = l + 64 * ob;
    if (oh < OUTHW) {
      float x = ((float)oh + 0.5f) * KSCALE - 0.5f;
      int jlo = (int)ceilf(x - KSCALE);  if (jlo < 0) jlo = 0;
      int jhi = (int)floorf(x + KSCALE); if (jhi > N - 1) jhi = N - 1;
      float ssum = 0.0f, acc = 0.0f, accm = 0.0f;
      for (int j = jlo; j <= jhi; ++j) {
        float wgt = 1.0f - fabsf((float)j - x) * SCALE;
        wgt = fmaxf(wgt, 0.0f);
        ssum += wgt;
        acc  += wgt * swav[LP(j)];
        accm += wgt * swav[LP((N - j) & (N - 1))];
      }
      float inv = 1.0f / ssum;
      T1[(size_t)sx * OUTHW + oh] = acc * inv;
      if (mir) T1[(size_t)(N - sx) * OUTHW + oh] = accm * inv;
    }
  }
}

// Pass 3: contract v (T1 rows contiguous per oh-window) + normalization.
__global__ __launch_bounds__(256) void k_resize2(const float2* __restrict__ A,
                                                 const int* __restrict__ mnmx,
                                                 float* __restrict__ out) {
  __shared__ float win[11 * OUTHW];
  const int ow = blockIdx.x % OUTHW;
  const int bc = blockIdx.x / OUTHW;
  const int b  = bc / CH;
  const int t  = threadIdx.x;
  const float* T1 = (const float*)(A + ((size_t)bc << 20)) + T1OFF;
  float x = ((float)ow + 0.5f) * KSCALE - 0.5f;
  int jlo = (int)ceilf(x - KSCALE);  if (jlo < 0) jlo = 0;
  int jhi = (int)floorf(x + KSCALE); if (jhi > N - 1) jhi = N - 1;
  const int nel = (jhi - jlo + 1) * OUTHW;
  const float* src = T1 + (size_t)jlo * OUTHW;
  for (int e = t; e < nel; e += 256) win[e] = src[e];
  __syncthreads();
  const float mn = __int_as_float(mnmx[b]);
  const float mx = __int_as_float(mnmx[BATCH + b]);
  const float inv = 1.0f / (mx - mn + 1e-8f);
  if (t < OUTHW) {
    float ssum = 0.0f, acc = 0.0f;
    for (int j = jlo; j <= jhi; ++j) {
      float wv = 1.0f - fabsf((float)j - x) * SCALE;
      wv = fmaxf(wv, 0.0f);
      ssum += wv;
      acc += wv * win[(j - jlo) * OUTHW + t];
    }
    float v = acc / ssum;
    out[((size_t)bc * OUTHW + t) * OUTHW + ow] = (v - mn) * inv;
  }
}

extern "C" void kernel_launch(void* const* d_in, const int* in_sizes, int n_in,
                              void* d_out, int out_size, void* d_ws, size_t ws_size,
                              hipStream_t stream) {
  const float* in = (const float*)d_in[0];
  float* out = (float*)d_out;
  float2* A = (float2*)d_ws;
  float* WSf = (float*)d_ws;
  int* mnmx = (int*)((char*)d_ws + ABYTES);
  float2* twg = (float2*)((char*)d_ws + ABYTES + 128);

  k_init<<<4, 256, 0, stream>>>(twg, mnmx);
  k_rowfft<<<BC * 128, 256, 0, stream>>>(in, A, twg);
  k_colfft<<<(BC * 513) / 4, 256, 0, stream>>>(A, WSf, mnmx, twg);
  k_resize2<<<BC * OUTHW, 256, 0, stream>>>(A, mnmx, out);
}